// Round 1
// baseline (483.753 us; speedup 1.0000x reference)
//
#include <hip/hip_runtime.h>

// LoRA forward, FUSED: out[8192][4096] = (x[8192][4096] @ A^T) @ B^T * 2.0, fp32.
// One block = 16 output rows. h[16][16] stays in LDS (never hits HBM):
//   Phase A: h = x_tile @ A^T via bf16 MFMA hi/lo split (err ~1e-5), K=4096
//            split 512-per-wave across 8 waves, cross-wave LDS reduce.
//   Phase B: out_tile = h @ B^T * 2 in fp32 VALU (B is L2-resident, 256 KB).
// Kills the previous 2-kernel structure's 16 MB hp write + 64 MB hp re-read +
// dispatch gap. Mandatory traffic: 128 MB x-read + 128 MB out-write (~40 us floor).

#define IN_F  4096
#define OUT_F 4096
#define RANK  16

typedef __attribute__((ext_vector_type(8))) short short8;   // 8 bf16 (4 VGPRs)
typedef __attribute__((ext_vector_type(4))) float f32x4;

static __device__ __forceinline__ short f2bf(float f) {
    union { float f; unsigned u; } v; v.f = f;
    unsigned r = v.u + 0x7fff + ((v.u >> 16) & 1);          // RNE
    return (short)(r >> 16);
}
static __device__ __forceinline__ float bf2f(short h) {
    union { unsigned u; float f; } v; v.u = ((unsigned)(unsigned short)h) << 16;
    return v.f;
}

// block = 512 threads (8 waves), grid = 512 blocks (2 blocks/CU at <=128 VGPR).
// frag layouts (16x16x32 bf16): A/B-frag idx=lane&15, k=(lane>>4)*8+j;
// D: col(n)=lane&15, row(m)=(lane>>4)*4+reg  -- verified in prior session.
__global__ __launch_bounds__(512, 4) void k_fused(const float* __restrict__ x,
                                                  const float* __restrict__ A,
                                                  const float* __restrict__ B,
                                                  float* __restrict__ out) {
    __shared__ float hpart[8][16][16];          // 8 KB: per-wave partial h
    __shared__ float hs[16 * RANK];             // 1 KB: reduced h * 2.0

    const int tid  = threadIdx.x;
    const int w    = __builtin_amdgcn_readfirstlane(tid >> 6);  // wave 0..7
    const int lane = tid & 63;
    const int n    = lane & 15;                 // x-row / A-rank within frag
    const int q    = lane >> 4;                 // k-quad
    const int row0 = blockIdx.x * 16;
    const int k0   = w * 512;                   // this wave's K slice

    // ---------------- Phase A: partial h = x_tile @ A^T (MFMA) ----------------
    f32x4 acc = {0.f, 0.f, 0.f, 0.f};
    const float* xr = x + (size_t)(row0 + n) * IN_F + k0 + q * 8;
    const float* ar = A + (size_t)n * IN_F + k0 + q * 8;

    for (int g = 0; g < 4; ++g) {               // 4 groups x 4 ktiles(32) = 512 k
        // issue all 16 loads for this group first (latency hiding)
        float4 a0[4], a1[4], v0[4], v1[4];
#pragma unroll
        for (int kt = 0; kt < 4; ++kt) {
            const float* ap = ar + (size_t)(g * 4 + kt) * 32;
            const float* xp = xr + (size_t)(g * 4 + kt) * 32;
            a0[kt] = *(const float4*)ap;
            a1[kt] = *(const float4*)(ap + 4);
            v0[kt] = *(const float4*)xp;
            v1[kt] = *(const float4*)(xp + 4);
        }
#pragma unroll
        for (int kt = 0; kt < 4; ++kt) {
            const float av[8] = {a0[kt].x, a0[kt].y, a0[kt].z, a0[kt].w,
                                 a1[kt].x, a1[kt].y, a1[kt].z, a1[kt].w};
            const float xv[8] = {v0[kt].x, v0[kt].y, v0[kt].z, v0[kt].w,
                                 v1[kt].x, v1[kt].y, v1[kt].z, v1[kt].w};
            short8 Ahi, Alo, xhi, xlo;
#pragma unroll
            for (int j = 0; j < 8; ++j) {
                const short ah = f2bf(av[j]);
                Ahi[j] = ah;
                Alo[j] = f2bf(av[j] - bf2f(ah));
                const short xh = f2bf(xv[j]);
                xhi[j] = xh;
                xlo[j] = f2bf(xv[j] - bf2f(xh));
            }
            acc = __builtin_amdgcn_mfma_f32_16x16x32_bf16(xhi, Ahi, acc, 0, 0, 0);
            acc = __builtin_amdgcn_mfma_f32_16x16x32_bf16(xlo, Ahi, acc, 0, 0, 0);
            acc = __builtin_amdgcn_mfma_f32_16x16x32_bf16(xhi, Alo, acc, 0, 0, 0);
        }
    }

    // D layout: col(rank)=n, row=q*4+r
#pragma unroll
    for (int r = 0; r < 4; ++r)
        hpart[w][q * 4 + r][n] = acc[r];
    __syncthreads();

    // cross-wave reduce: thread t owns (row,rank)=t; fold in SCALING=2.0
    if (tid < 256) {
        const float* hp = &hpart[0][0][0];
        float s = 0.f;
#pragma unroll
        for (int ww = 0; ww < 8; ++ww)
            s += hp[ww * 256 + tid];
        hs[tid] = 2.0f * s;
    }
    __syncthreads();

    // ---------------- Phase B: out_tile = h @ B^T (fp32 VALU) ----------------
    // thread t covers cols {t*4 .. t*4+3} in each 2048-col half.
#pragma unroll
    for (int half = 0; half < 2; ++half) {
        const int col = half * 2048 + tid * 4;
        // B slice into regs: bf[j*16 + rho] = B[col+j][rho]
        float4 breg[16];
        const float4* B4 = (const float4*)(B + (size_t)col * RANK);
#pragma unroll
        for (int i = 0; i < 16; ++i) breg[i] = B4[i];
        const float* bf = (const float*)breg;

        for (int r = 0; r < 16; ++r) {
            const float4 h0 = *(const float4*)(hs + r * RANK);
            const float4 h1 = *(const float4*)(hs + r * RANK + 4);
            const float4 h2 = *(const float4*)(hs + r * RANK + 8);
            const float4 h3 = *(const float4*)(hs + r * RANK + 12);
            const float hv[16] = {h0.x, h0.y, h0.z, h0.w, h1.x, h1.y, h1.z, h1.w,
                                  h2.x, h2.y, h2.z, h2.w, h3.x, h3.y, h3.z, h3.w};
            float4 o = {0.f, 0.f, 0.f, 0.f};
#pragma unroll
            for (int rho = 0; rho < RANK; ++rho) {
                o.x += hv[rho] * bf[0 * RANK + rho];
                o.y += hv[rho] * bf[1 * RANK + rho];
                o.z += hv[rho] * bf[2 * RANK + rho];
                o.w += hv[rho] * bf[3 * RANK + rho];
            }
            *(float4*)(out + (size_t)(row0 + r) * OUT_F + col) = o;  // dwordx4
        }
    }
}

extern "C" void kernel_launch(void* const* d_in, const int* in_sizes, int n_in,
                              void* d_out, int out_size, void* d_ws, size_t ws_size,
                              hipStream_t stream) {
    const float* x  = (const float*)d_in[0];   // [4,2048,4096]
    const float* A  = (const float*)d_in[1];   // [16,4096]
    const float* Bm = (const float*)d_in[2];   // [4096,16]
    float* out = (float*)d_out;                // [8192,4096] fp32

    k_fused<<<512, 512, 0, stream>>>(x, A, Bm, out);
}